// Round 15
// baseline (249.979 us; speedup 1.0000x reference)
//
#include <hip/hip_runtime.h>
#include <hip/hip_bf16.h>

#define NE 8
#define HD 1024
#define ID 2816
#define TT 4096
#define BM 128
#define BK 32
#define BN1 128
#define BN2 128
#define MAXMT (TT / BM + NE) /* 40 worst-case M-tiles */
#define NKS1 (HD / BK)  /* 32 */
#define NKS2 (ID / BK)  /* 88 */
#define ATILE 8192      /* BM*BK*2B fragment-order A tile */
#define GS 1040         /* B group stride (16B pad -> conflict-free writes) */
#define BT (8 * GS)     /* 8320 B per B tile (8 groups of 16 cols) */

typedef __attribute__((ext_vector_type(4))) float f32x4;
typedef __attribute__((ext_vector_type(8))) short s16x8;

// fp32x2 -> packed bf16x2 (RNE, v_cvt_pk_bf16_f32)
__device__ __forceinline__ unsigned int f2bfpk(float lo, float hi) {
  float2 t; t.x = lo; t.y = hi;
  union { __hip_bfloat162 h2; unsigned int u; } cv;
  cv.h2 = __float22bfloat162_rn(t);
  return cv.u;
}

// async global->LDS, 16B per lane
__device__ __forceinline__ void glds16(const void* g, void* l) {
  __builtin_amdgcn_global_load_lds(
      (const __attribute__((address_space(1))) void*)g,
      (__attribute__((address_space(3))) void*)l, 16, 0, 0);
}

__device__ __forceinline__ bool map_tile(const void* bsp, int mt, int& e,
                                         int& mstart, int& rowend) {
  const int* w = (const int*)bsp;
  bool is64 = (w[1] == 0) && (w[3] == 0) && (w[5] == 0) && (w[7] == 0) &&
              ((w[0] | w[2] | w[4] | w[6]) != 0);
  long long start = 0;
  int rem = mt;
  for (int i = 0; i < NE; ++i) {
    long long b = is64 ? ((const long long*)bsp)[i] : (long long)w[i];
    if (b < 0) b = 0;
    int tiles = (int)((b + BM - 1) / BM);
    if (rem < tiles) {
      long long m0 = start + (long long)rem * BM;
      long long me = start + b;
      if (m0 >= TT) return false;
      if (me > TT) me = TT;
      e = i; mstart = (int)m0; rowend = (int)me;
      return true;
    }
    rem -= tiles;
    start += b;
  }
  return false;
}

// ---- Kernel 0: x fp32 -> bf16, pre-tiled in MFMA fragment order ----
__global__ __launch_bounds__(256) void cvt_xt(const float* __restrict__ x,
                                              const void* __restrict__ bsp,
                                              unsigned short* __restrict__ xt) {
  int mt = blockIdx.x >> 5;
  int ks = blockIdx.x & 31;
  int e, mstart, rowend;
  if (!map_tile(bsp, mt, e, mstart, rowend)) return;
  int t = threadIdx.x;
  int lane = t & 63;
  int r = lane & 15, q = lane >> 4;
  unsigned short* ob = xt + ((size_t)mt * NKS1 + ks) * (ATILE / 2);
#pragma unroll
  for (int h = 0; h < 2; ++h) {
    int f = h * 4 + (t >> 6);
    int row = mstart + f * 16 + r;
    s16x8 o = (s16x8)0;
    if (row < rowend) {
      const float* src = x + (size_t)row * HD + ks * 32 + q * 8;
      f32x4 v0 = *(const f32x4*)src;
      f32x4 v1 = *(const f32x4*)(src + 4);
      unsigned int d0 = f2bfpk(v0[0], v0[1]), d1 = f2bfpk(v0[2], v0[3]);
      unsigned int d2 = f2bfpk(v1[0], v1[1]), d3 = f2bfpk(v1[2], v1[3]);
      o[0] = (short)d0; o[1] = (short)(d0 >> 16);
      o[2] = (short)d1; o[3] = (short)(d1 >> 16);
      o[4] = (short)d2; o[5] = (short)(d2 >> 16);
      o[6] = (short)d3; o[7] = (short)(d3 >> 16);
    }
    *(s16x8*)(ob + h * 2048 + t * 8) = o;
  }
}

// ---------------- Kernel 1: up = silu(x@w1[e]) * (x@w3[e]) ----------------
// THIS ROUND: 128x128 tile, 512 thr / 8 waves (2M x 4N, 64x32/wave, dual
// acc = 64 VGPR). Per phase: MFMA work 2x, staging instrs/wave halved
// (A = ONE 8KB glds call; B = 4 dwordx4/thread covering 2x cols). 1-deep
// W regs (16) to stay under the (512,4) 128-VGPR cap -- round 6's spill
// lesson. 48.5KB LDS -> 2 blocks/CU by VGPR, 16 waves/CU.
__global__ __launch_bounds__(512, 4) void moe_gemm1(
    const unsigned short* __restrict__ xt, const float* __restrict__ w1,
    const float* __restrict__ w3, const void* __restrict__ bsp,
    __hip_bfloat16* __restrict__ up) {
  __shared__ __align__(16) char As[2][ATILE];  // 16384
  __shared__ __align__(16) char B1s[2][BT];    // 16640
  __shared__ __align__(16) char B3s[2][BT];    // 16640 -> 48.5KB

  const int NWG = (ID / BN1) * MAXMT;  // 22*40 = 880, %8==0
  int bid = blockIdx.x;
  int logical = (bid & 7) * (NWG >> 3) + (bid >> 3);
  int mt = logical % MAXMT;            // mt-inner (L2 weight-slab sharing)
  int nt = logical / MAXMT;
  int e, mstart, rowend;
  if (!map_tile(bsp, mt, e, mstart, rowend)) return;
  const int n0 = nt * BN1;
  const int tid = threadIdx.x;
  const int lane = tid & 63;
  const int wv = tid >> 6;                  // 0..7
  const int wr = wv >> 2, wc = wv & 3;      // 2M x 4N
  const int q = lane >> 4, r16 = lane & 15;

  // B staging: thread owns cols c4*4..+3, k = 2*kb, 2*kb+1
  const int c4 = tid & 31, kb = tid >> 5;   // c4 0..31, kb 0..15
  const int wbase = (c4 >> 2) * GS + (kb >> 2) * 256 + (kb & 3) * 4;
  const int wcol = (c4 & 3) * 4;            // write at wbase + (wcol+ci)*16
  const char* agp = (const char*)xt + (size_t)mt * NKS1 * ATILE + tid * 16;
  const float* w1c = w1 + (size_t)e * HD * ID + (size_t)(2 * kb) * ID + n0 + c4 * 4;
  const float* w3c = w3 + (size_t)e * HD * ID + (size_t)(2 * kb) * ID + n0 + c4 * 4;

  f32x4 acc1[4][2], acc3[4][2];
#pragma unroll
  for (int i = 0; i < 4; ++i)
#pragma unroll
    for (int j = 0; j < 2; ++j) { acc1[i][j] = (f32x4)0.f; acc3[i][j] = (f32x4)0.f; }

  f32x4 W1[2], W3[2];  // 1-deep: k, k+1 rows of 4 cols

  auto gldsA = [&](int k, int buf) {
    glds16(agp + (size_t)k * ATILE, &As[buf][0] + tid * 16);
  };
  auto loadB = [&]() {
    W1[0] = *(const f32x4*)w1c;
    W1[1] = *(const f32x4*)(w1c + ID);
    W3[0] = *(const f32x4*)w3c;
    W3[1] = *(const f32x4*)(w3c + ID);
    w1c += (size_t)BK * ID; w3c += (size_t)BK * ID;
  };
  auto storeB = [&](int buf) {
#pragma unroll
    for (int ci = 0; ci < 4; ++ci) {
      *(unsigned int*)(B1s[buf] + wbase + (wcol + ci) * 16) = f2bfpk(W1[0][ci], W1[1][ci]);
      *(unsigned int*)(B3s[buf] + wbase + (wcol + ci) * 16) = f2bfpk(W3[0][ci], W3[1][ci]);
    }
  };
  auto compute = [&](int ab, int bb) {
    s16x8 a[4], b1[2], b3[2];
#pragma unroll
    for (int i = 0; i < 4; ++i)
      a[i] = *(const s16x8*)(As[ab] + (wr * 4 + i) * 1024 + lane * 16);
#pragma unroll
    for (int j = 0; j < 2; ++j) {
      b1[j] = *(const s16x8*)(B1s[bb] + (wc * 2 + j) * GS + lane * 16);
      b3[j] = *(const s16x8*)(B3s[bb] + (wc * 2 + j) * GS + lane * 16);
    }
    __builtin_amdgcn_s_setprio(1);
#pragma unroll
    for (int i = 0; i < 4; ++i)
#pragma unroll
      for (int j = 0; j < 2; ++j) {
        acc1[i][j] = __builtin_amdgcn_mfma_f32_16x16x32_bf16(a[i], b1[j], acc1[i][j], 0, 0, 0);
        acc3[i][j] = __builtin_amdgcn_mfma_f32_16x16x32_bf16(a[i], b3[j], acc3[i][j], 0, 0, 0);
      }
    __builtin_amdgcn_s_setprio(0);
  };

// phase k (P=k&1): loadB W(k+1), glds A(k+1)->As[P^1], compute(k),
// storeB(P^1) [implicit vmcnt for W], drain, barrier.
#define G1PHASE(P, KC)                                                    \
  {                                                                       \
    const bool nx = (kt + (KC) + 1 < NKS1);                               \
    if (nx) {                                                             \
      loadB();                                                            \
      __builtin_amdgcn_sched_barrier(0);                                  \
      gldsA(kt + (KC) + 1, (P) ^ 1);                                      \
      __builtin_amdgcn_sched_barrier(0);                                  \
    }                                                                     \
    compute((P), (P));                                                    \
    if (nx) {                                                             \
      storeB((P) ^ 1);                                                    \
      asm volatile("s_waitcnt vmcnt(0) lgkmcnt(0)" ::: "memory");         \
      __builtin_amdgcn_s_barrier();                                       \
    }                                                                     \
  }

  // prologue: stage tile 0
  loadB();
  __builtin_amdgcn_sched_barrier(0);
  gldsA(0, 0);
  storeB(0);
  asm volatile("s_waitcnt vmcnt(0) lgkmcnt(0)" ::: "memory");
  __builtin_amdgcn_s_barrier();

  for (int kt = 0; kt < NKS1; kt += 2) {
    G1PHASE(0, 0)
    G1PHASE(1, 1)
  }
#undef G1PHASE

  // epilogue: silu(acc1)*acc3 -> bf16
#pragma unroll
  for (int i = 0; i < 4; ++i)
#pragma unroll
    for (int r = 0; r < 4; ++r) {
      int gm = mstart + wr * 64 + i * 16 + q * 4 + r;
      if (gm < rowend) {
#pragma unroll
        for (int j = 0; j < 2; ++j) {
          float v1 = acc1[i][j][r], v3 = acc3[i][j][r];
          float s = v1 / (1.f + __expf(-v1));
          up[(size_t)gm * ID + n0 + wc * 32 + j * 16 + r16] = __float2bfloat16(s * v3);
        }
      }
    }
}

// ---------------- Kernel 2: out = up @ w2[e] ----------------
// Same 128x128 / 512-thr / 8-wave geometry, single acc (32 VGPR).
// Grid real = 256 blocks = exactly one round. A glds'd from row-major up
// (per-lane frag-order sources, one call/phase). 33KB LDS.
__global__ __launch_bounds__(512, 4) void moe_gemm2(
    const __hip_bfloat16* __restrict__ up, const float* __restrict__ w2,
    const void* __restrict__ bsp, float* __restrict__ out) {
  __shared__ __align__(16) char As[2][ATILE];  // 16384
  __shared__ __align__(16) char Bs[2][BT];     // 16640 -> 33KB

  const int NWG = (HD / BN2) * MAXMT;  // 8*40 = 320, %8==0
  int bid = blockIdx.x;
  int logical = (bid & 7) * (NWG >> 3) + (bid >> 3);
  int mt = logical % MAXMT;
  int nt = logical / MAXMT;
  int e, mstart, rowend;
  if (!map_tile(bsp, mt, e, mstart, rowend)) return;
  const int n0 = nt * BN2;
  const int tid = threadIdx.x;
  const int lane = tid & 63;
  const int wv = tid >> 6;
  const int wr = wv >> 2, wc = wv & 3;
  const int q = lane >> 4, r16 = lane & 15;

  const int c4 = tid & 31, kb = tid >> 5;
  const int wbase = (c4 >> 2) * GS + (kb >> 2) * 256 + (kb & 3) * 4;
  const int wcol = (c4 & 3) * 4;
  const float* w2c = w2 + (size_t)e * ID * HD + (size_t)(2 * kb) * HD + n0 + c4 * 4;

  // glds A source: thread = (group tid>>6, row r, k-offset q*8); row clamped
  int row0 = mstart + (tid >> 6) * 16 + (tid & 15);
  row0 = row0 < TT ? row0 : TT - 1;
  const char* uc0 = (const char*)up + ((size_t)row0 * ID + ((tid >> 4) & 3) * 8) * 2;

  f32x4 acc[4][2];
#pragma unroll
  for (int i = 0; i < 4; ++i)
#pragma unroll
    for (int j = 0; j < 2; ++j) acc[i][j] = (f32x4)0.f;

  f32x4 W[2];

  auto gldsA = [&](int buf) {  // sequential k; cursor advances 64B/call
    glds16(uc0, &As[buf][0] + tid * 16);
    uc0 += BK * 2;
  };
  auto loadB = [&]() {
    W[0] = *(const f32x4*)w2c;
    W[1] = *(const f32x4*)(w2c + HD);
    w2c += (size_t)BK * HD;
  };
  auto storeB = [&](int buf) {
#pragma unroll
    for (int ci = 0; ci < 4; ++ci)
      *(unsigned int*)(Bs[buf] + wbase + (wcol + ci) * 16) = f2bfpk(W[0][ci], W[1][ci]);
  };
  auto compute = [&](int ab, int bb) {
    s16x8 a[4], b[2];
#pragma unroll
    for (int i = 0; i < 4; ++i)
      a[i] = *(const s16x8*)(As[ab] + (wr * 4 + i) * 1024 + lane * 16);
#pragma unroll
    for (int j = 0; j < 2; ++j)
      b[j] = *(const s16x8*)(Bs[bb] + (wc * 2 + j) * GS + lane * 16);
    __builtin_amdgcn_s_setprio(1);
#pragma unroll
    for (int i = 0; i < 4; ++i)
#pragma unroll
      for (int j = 0; j < 2; ++j)
        acc[i][j] = __builtin_amdgcn_mfma_f32_16x16x32_bf16(a[i], b[j], acc[i][j], 0, 0, 0);
    __builtin_amdgcn_s_setprio(0);
  };

#define G2PHASE(P, KC)                                                    \
  {                                                                       \
    const bool nx = (kt + (KC) + 1 < NKS2);                               \
    if (nx) {                                                             \
      loadB();                                                            \
      __builtin_amdgcn_sched_barrier(0);                                  \
      gldsA((P) ^ 1);                                                     \
      __builtin_amdgcn_sched_barrier(0);                                  \
    }                                                                     \
    compute((P), (P));                                                    \
    if (nx) {                                                             \
      storeB((P) ^ 1);                                                    \
      asm volatile("s_waitcnt vmcnt(0) lgkmcnt(0)" ::: "memory");         \
      __builtin_amdgcn_s_barrier();                                       \
    }                                                                     \
  }

  loadB();
  __builtin_amdgcn_sched_barrier(0);
  gldsA(0);
  storeB(0);
  asm volatile("s_waitcnt vmcnt(0) lgkmcnt(0)" ::: "memory");
  __builtin_amdgcn_s_barrier();

  for (int kt = 0; kt < NKS2; kt += 2) {
    G2PHASE(0, 0)
    G2PHASE(1, 1)
  }
#undef G2PHASE

#pragma unroll
  for (int i = 0; i < 4; ++i)
#pragma unroll
    for (int r = 0; r < 4; ++r) {
      int gm = mstart + wr * 64 + i * 16 + q * 4 + r;
      if (gm < rowend) {
#pragma unroll
        for (int j = 0; j < 2; ++j)
          out[(size_t)gm * HD + n0 + wc * 32 + j * 16 + r16] = acc[i][j][r];
      }
    }
}

extern "C" void kernel_launch(void* const* d_in, const int* in_sizes, int n_in,
                              void* d_out, int out_size, void* d_ws, size_t ws_size,
                              hipStream_t stream) {
  const float* x = (const float*)d_in[0];
  const float* w1 = (const float*)d_in[1];
  const float* w2 = (const float*)d_in[2];
  const float* w3 = (const float*)d_in[3];
  const void* bs = d_in[4];
  float* out = (float*)d_out;
  // ws: xt tiled [10.49 MB] | up [23.07 MB]
  unsigned short* xt = (unsigned short*)d_ws;
  __hip_bfloat16* up =
      (__hip_bfloat16*)((char*)d_ws + (size_t)MAXMT * NKS1 * ATILE);

  hipMemsetAsync(d_out, 0, (size_t)out_size * sizeof(float), stream);

  cvt_xt<<<dim3(MAXMT * NKS1), dim3(256), 0, stream>>>(x, bs, xt);
  moe_gemm1<<<dim3((ID / BN1) * MAXMT), dim3(512), 0, stream>>>(xt, w1, w3, bs, up);
  moe_gemm2<<<dim3((HD / BN2) * MAXMT), dim3(512), 0, stream>>>(up, w2, bs, out);
}

// Round 16
// 249.020 us; speedup vs baseline: 1.0038x; 1.0038x over previous
//
#include <hip/hip_runtime.h>
#include <hip/hip_bf16.h>

#define NE 8
#define HD 1024
#define ID 2816
#define TT 4096
#define BM 256
#define BK 32
#define BN1 64
#define BN2 64
#define MAXMT (TT / BM + NE) /* 24 worst-case 256-row M-tiles */
#define NKS1 (HD / BK)  /* 32 */
#define NKS2 (ID / BK)  /* 88 */
#define ATILE 8192      /* 128 rows x 32 k bf16, fragment order */
#define TILE2 (2 * ATILE) /* 16KB: 256-row A tile */
#define GS 1040         /* B group stride (16B pad) */
#define BT (4 * GS)     /* BN=64 -> 4 groups = 4160 B */

typedef __attribute__((ext_vector_type(4))) float f32x4;
typedef __attribute__((ext_vector_type(8))) short s16x8;

// fp32x2 -> packed bf16x2 (RNE, v_cvt_pk_bf16_f32)
__device__ __forceinline__ unsigned int f2bfpk(float lo, float hi) {
  float2 t; t.x = lo; t.y = hi;
  union { __hip_bfloat162 h2; unsigned int u; } cv;
  cv.h2 = __float22bfloat162_rn(t);
  return cv.u;
}

// async global->LDS, 16B per lane (dest MUST be wavebase + lane*16)
__device__ __forceinline__ void glds16(const void* g, void* l) {
  __builtin_amdgcn_global_load_lds(
      (const __attribute__((address_space(1))) void*)g,
      (__attribute__((address_space(3))) void*)l, 16, 0, 0);
}

__device__ __forceinline__ bool map_tile(const void* bsp, int mt, int& e,
                                         int& mstart, int& rowend) {
  const int* w = (const int*)bsp;
  bool is64 = (w[1] == 0) && (w[3] == 0) && (w[5] == 0) && (w[7] == 0) &&
              ((w[0] | w[2] | w[4] | w[6]) != 0);
  long long start = 0;
  int rem = mt;
  for (int i = 0; i < NE; ++i) {
    long long b = is64 ? ((const long long*)bsp)[i] : (long long)w[i];
    if (b < 0) b = 0;
    int tiles = (int)((b + BM - 1) / BM);
    if (rem < tiles) {
      long long m0 = start + (long long)rem * BM;
      long long me = start + b;
      if (m0 >= TT) return false;
      if (me > TT) me = TT;
      e = i; mstart = (int)m0; rowend = (int)me;
      return true;
    }
    rem -= tiles;
    start += b;
  }
  return false;
}

// ---- Kernel 0: x fp32 -> bf16, 256-row fragment-order tiles ----
// [mt][ks][half 0|1][group f=0..7][lane][8 bf16]; rows >= rowend zeroed.
__global__ __launch_bounds__(256) void cvt_xt(const float* __restrict__ x,
                                              const void* __restrict__ bsp,
                                              unsigned short* __restrict__ xt) {
  int mt = blockIdx.x >> 5;
  int ks = blockIdx.x & 31;
  int e, mstart, rowend;
  if (!map_tile(bsp, mt, e, mstart, rowend)) return;
  int t = threadIdx.x;
  int lane = t & 63;
  int r = lane & 15, q = lane >> 4;
  unsigned short* ob = xt + ((size_t)mt * NKS1 + ks) * (TILE2 / 2);
#pragma unroll
  for (int hh = 0; hh < 4; ++hh) {
    int half = hh >> 1, fq = hh & 1;
    int f = fq * 4 + (t >> 6);
    int row = mstart + half * 128 + f * 16 + r;
    s16x8 o = (s16x8)0;
    if (row < rowend) {
      const float* src = x + (size_t)row * HD + ks * 32 + q * 8;
      f32x4 v0 = *(const f32x4*)src;
      f32x4 v1 = *(const f32x4*)(src + 4);
      unsigned int d0 = f2bfpk(v0[0], v0[1]), d1 = f2bfpk(v0[2], v0[3]);
      unsigned int d2 = f2bfpk(v1[0], v1[1]), d3 = f2bfpk(v1[2], v1[3]);
      o[0] = (short)d0; o[1] = (short)(d0 >> 16);
      o[2] = (short)d1; o[3] = (short)(d1 >> 16);
      o[4] = (short)d2; o[5] = (short)(d2 >> 16);
      o[6] = (short)d3; o[7] = (short)(d3 >> 16);
    }
    *(s16x8*)(ob + half * 4096 + fq * 2048 + t * 8) = o;
  }
}

// ---------------- Kernel 1: up = silu(x@w1[e]) * (x@w3[e]) ----------------
// 256x64 tile, 512 thr / 8 waves (4m x 2n, 64x32/wave, dual acc = 64 VGPR).
// Weight bytes per output element: 2.0 B (was 5.0) -- TA-bandwidth theory.
// Waves 0-3 stage w1, 4-7 stage w3 (1 f32x4-pair + 4 b32 frag-writes/thr).
// Counted-vmcnt ring: glds(p+1), loadB(p+2), compute(p), storeB(p+1),
// vmcnt(2) [drains glds, W stays in flight], barrier. (512,2): 256-VGPR cap.
__global__ __launch_bounds__(512, 2) void moe_gemm1(
    const unsigned short* __restrict__ xt, const float* __restrict__ w1,
    const float* __restrict__ w3, const void* __restrict__ bsp,
    __hip_bfloat16* __restrict__ up) {
  __shared__ __align__(16) char As[2][TILE2];  // 32768
  __shared__ __align__(16) char B1s[2][BT];    // 8320
  __shared__ __align__(16) char B3s[2][BT];    // 8320  -> 49.4KB

  const int NWG = (ID / BN1) * MAXMT;  // 44*24 = 1056, %8==0
  int bid = blockIdx.x;
  int logical = (bid & 7) * (NWG >> 3) + (bid >> 3);
  int mt = logical % MAXMT;            // mt-inner (L2 weight-slab sharing)
  int nt = logical / MAXMT;
  int e, mstart, rowend;
  if (!map_tile(bsp, mt, e, mstart, rowend)) return;
  const int n0 = nt * BN1;
  const int tid = threadIdx.x;
  const int lane = tid & 63;
  const int wv = tid >> 6;                 // 0..7
  const int wr = wv >> 1, wc = wv & 1;     // 4m x 2n
  const int q = lane >> 4, r16 = lane & 15;

  // B staging: half = tid>>8 (0:w1, 1:w3); t8 thread covers 4 cols x 2 k
  const int t8 = tid & 255;
  const int c4 = t8 & 15, kp = t8 >> 4;    // c4 col-quad, kp k-pair 0..15
  const int wbase = (c4 >> 2) * GS + (kp >> 2) * 256 + (kp & 3) * 4;
  const int wcol = (c4 & 3) * 4;
  const char* agp = (const char*)xt + (size_t)mt * NKS1 * TILE2 + tid * 16;
  const float* wsrc = ((tid & 256) ? w3 : w1) + (size_t)e * HD * ID +
                      (size_t)(2 * kp) * ID + n0 + c4 * 4;
  char* bdst0 = (tid & 256) ? B3s[0] : B1s[0];
  char* bdst1 = (tid & 256) ? B3s[1] : B1s[1];

  f32x4 acc1[4][2], acc3[4][2];
#pragma unroll
  for (int i = 0; i < 4; ++i)
#pragma unroll
    for (int j = 0; j < 2; ++j) { acc1[i][j] = (f32x4)0.f; acc3[i][j] = (f32x4)0.f; }

  f32x4 Wa[2], Wb[2];  // 2-deep W ring (k row, k+1 row of 4 cols)

  auto gldsA = [&](int k, int buf) {
    const char* s = agp + (size_t)k * TILE2;
    char* d = &As[buf][0] + tid * 16;
    glds16(s, d);
    glds16(s + ATILE, d + ATILE);
  };
  auto loadB = [&](f32x4* W) {
    W[0] = *(const f32x4*)wsrc;
    W[1] = *(const f32x4*)(wsrc + ID);
    wsrc += (size_t)BK * ID;
  };
  auto storeB = [&](int buf, const f32x4* W) {
    char* b = buf ? bdst1 : bdst0;
#pragma unroll
    for (int ci = 0; ci < 4; ++ci)
      *(unsigned int*)(b + wbase + (wcol + ci) * 16) = f2bfpk(W[0][ci], W[1][ci]);
  };
  auto compute = [&](int ab, int bb) {
    s16x8 a[4], b1[2], b3[2];
#pragma unroll
    for (int i = 0; i < 4; ++i)
      a[i] = *(const s16x8*)(As[ab] + (wr >> 1) * ATILE +
                             ((wr & 1) * 4 + i) * 1024 + lane * 16);
#pragma unroll
    for (int j = 0; j < 2; ++j) {
      b1[j] = *(const s16x8*)(B1s[bb] + (wc * 2 + j) * GS + lane * 16);
      b3[j] = *(const s16x8*)(B3s[bb] + (wc * 2 + j) * GS + lane * 16);
    }
    __builtin_amdgcn_s_setprio(1);
#pragma unroll
    for (int i = 0; i < 4; ++i)
#pragma unroll
      for (int j = 0; j < 2; ++j) {
        acc1[i][j] = __builtin_amdgcn_mfma_f32_16x16x32_bf16(a[i], b1[j], acc1[i][j], 0, 0, 0);
        acc3[i][j] = __builtin_amdgcn_mfma_f32_16x16x32_bf16(a[i], b3[j], acc3[i][j], 0, 0, 0);
      }
    __builtin_amdgcn_s_setprio(0);
  };

#define G1PHASE(P, KC)                                                    \
  {                                                                       \
    const bool doG = (kt + (KC) + 1 < NKS1);                              \
    const bool doL = (kt + (KC) + 2 < NKS1);                              \
    if (doG) {                                                            \
      gldsA(kt + (KC) + 1, (P) ^ 1);                                      \
      __builtin_amdgcn_sched_barrier(0);                                  \
    }                                                                     \
    if (doL) {                                                            \
      loadB((P) ? Wb : Wa);                                               \
      __builtin_amdgcn_sched_barrier(0);                                  \
    }                                                                     \
    compute((P), (P));                                                    \
    if (doG) {                                                            \
      storeB((P) ^ 1, (P) ? Wa : Wb);                                     \
      if (doL)                                                            \
        asm volatile("s_waitcnt vmcnt(2) lgkmcnt(0)" ::: "memory");       \
      else                                                                \
        asm volatile("s_waitcnt vmcnt(0) lgkmcnt(0)" ::: "memory");       \
      __builtin_amdgcn_s_barrier();                                       \
    }                                                                     \
  }

  // prologue: glds(0); W(0)->Wa; W(1)->Wb; storeB(0,Wa); drain glds; barrier
  gldsA(0, 0);
  __builtin_amdgcn_sched_barrier(0);
  loadB(Wa);
  __builtin_amdgcn_sched_barrier(0);
  loadB(Wb);
  storeB(0, Wa);
  asm volatile("s_waitcnt vmcnt(2) lgkmcnt(0)" ::: "memory");
  __builtin_amdgcn_s_barrier();

  for (int kt = 0; kt < NKS1; kt += 2) {
    G1PHASE(0, 0)
    G1PHASE(1, 1)
  }
#undef G1PHASE

  // epilogue: silu(acc1)*acc3 -> bf16
#pragma unroll
  for (int i = 0; i < 4; ++i)
#pragma unroll
    for (int r = 0; r < 4; ++r) {
      int gm = mstart + wr * 64 + i * 16 + q * 4 + r;
      if (gm < rowend) {
#pragma unroll
        for (int j = 0; j < 2; ++j) {
          float v1 = acc1[i][j][r], v3 = acc3[i][j][r];
          float s = v1 / (1.f + __expf(-v1));
          up[(size_t)gm * ID + n0 + wc * 32 + j * 16 + r16] = __float2bfloat16(s * v3);
        }
      }
    }
}

// ---------------- Kernel 2: out = up @ w2[e] ----------------
// 256x64 tile, 512 thr / 8 waves (4m x 2n), single acc. A glds'd from
// row-major up (2 calls/phase, per-lane frag-order sources). B staged by
// threads 0-255 only (waves 0-3; wave-uniform guard). 40.6KB LDS.
__global__ __launch_bounds__(512, 2) void moe_gemm2(
    const __hip_bfloat16* __restrict__ up, const float* __restrict__ w2,
    const void* __restrict__ bsp, float* __restrict__ out) {
  __shared__ __align__(16) char As[2][TILE2];  // 32768
  __shared__ __align__(16) char Bs[2][BT];     // 8320 -> 40.6KB

  const int NWG = (HD / BN2) * MAXMT;  // 16*24 = 384, %8==0
  int bid = blockIdx.x;
  int logical = (bid & 7) * (NWG >> 3) + (bid >> 3);
  int mt = logical % MAXMT;
  int nt = logical / MAXMT;
  int e, mstart, rowend;
  if (!map_tile(bsp, mt, e, mstart, rowend)) return;
  const int n0 = nt * BN2;
  const int tid = threadIdx.x;
  const int lane = tid & 63;
  const int wv = tid >> 6;
  const int wr = wv >> 1, wc = wv & 1;
  const int q = lane >> 4, r16 = lane & 15;

  // B staging (threads 0-255): 4 cols x 2 k per thread
  const int c4 = tid & 15, kp = (tid >> 4) & 15;
  const int wbase = (c4 >> 2) * GS + (kp >> 2) * 256 + (kp & 3) * 4;
  const int wcol = (c4 & 3) * 4;
  const float* wsrc = w2 + (size_t)e * ID * HD + (size_t)(2 * kp) * HD + n0 + c4 * 4;

  // A glds sources: call h covers rows half h (128 rows, frag order)
  const char* uc[2];
#pragma unroll
  for (int h = 0; h < 2; ++h) {
    int row = mstart + h * 128 + ((tid >> 6) * 16) + (tid & 15);
    row = row < TT ? row : TT - 1;
    uc[h] = (const char*)up + ((size_t)row * ID + ((tid >> 4) & 3) * 8) * 2;
  }

  f32x4 acc[4][2];
#pragma unroll
  for (int i = 0; i < 4; ++i)
#pragma unroll
    for (int j = 0; j < 2; ++j) acc[i][j] = (f32x4)0.f;

  f32x4 Wa[2], Wb[2];

  auto gldsA = [&](int buf) {  // sequential k; cursors advance 64B/call
    char* d = &As[buf][0] + tid * 16;
    glds16(uc[0], d);
    glds16(uc[1], d + ATILE);
    uc[0] += BK * 2; uc[1] += BK * 2;
  };
  auto loadB = [&](f32x4* W) {
    if (tid < 256) {
      W[0] = *(const f32x4*)wsrc;
      W[1] = *(const f32x4*)(wsrc + HD);
    }
    wsrc += (size_t)BK * HD;
  };
  auto storeB = [&](int buf, const f32x4* W) {
    if (tid < 256) {
#pragma unroll
      for (int ci = 0; ci < 4; ++ci)
        *(unsigned int*)(Bs[buf] + wbase + (wcol + ci) * 16) = f2bfpk(W[0][ci], W[1][ci]);
    }
  };
  auto compute = [&](int ab, int bb) {
    s16x8 a[4], b[2];
#pragma unroll
    for (int i = 0; i < 4; ++i)
      a[i] = *(const s16x8*)(As[ab] + (wr >> 1) * ATILE +
                             ((wr & 1) * 4 + i) * 1024 + lane * 16);
#pragma unroll
    for (int j = 0; j < 2; ++j)
      b[j] = *(const s16x8*)(Bs[bb] + (wc * 2 + j) * GS + lane * 16);
    __builtin_amdgcn_s_setprio(1);
#pragma unroll
    for (int i = 0; i < 4; ++i)
#pragma unroll
      for (int j = 0; j < 2; ++j)
        acc[i][j] = __builtin_amdgcn_mfma_f32_16x16x32_bf16(a[i], b[j], acc[i][j], 0, 0, 0);
    __builtin_amdgcn_s_setprio(0);
  };

#define G2PHASE(P, KC)                                                    \
  {                                                                       \
    const bool doG = (kt + (KC) + 1 < NKS2);                              \
    const bool doL = (kt + (KC) + 2 < NKS2);                              \
    if (doG) {                                                            \
      gldsA((P) ^ 1);                                                     \
      __builtin_amdgcn_sched_barrier(0);                                  \
    }                                                                     \
    if (doL) {                                                            \
      loadB((P) ? Wb : Wa);                                               \
      __builtin_amdgcn_sched_barrier(0);                                  \
    }                                                                     \
    compute((P), (P));                                                    \
    if (doG) {                                                            \
      storeB((P) ^ 1, (P) ? Wa : Wb);                                     \
      if (doL)                                                            \
        asm volatile("s_waitcnt vmcnt(2) lgkmcnt(0)" ::: "memory");       \
      else                                                                \
        asm volatile("s_waitcnt vmcnt(0) lgkmcnt(0)" ::: "memory");       \
      __builtin_amdgcn_s_barrier();                                       \
    }                                                                     \
  }

  gldsA(0);
  __builtin_amdgcn_sched_barrier(0);
  loadB(Wa);
  __builtin_amdgcn_sched_barrier(0);
  loadB(Wb);
  storeB(0, Wa);
  asm volatile("s_waitcnt vmcnt(2) lgkmcnt(0)" ::: "memory");
  __builtin_amdgcn_s_barrier();

  for (int kt = 0; kt < NKS2; kt += 2) {
    G2PHASE(0, 0)
    G2PHASE(1, 1)
  }
#undef G2PHASE

#pragma unroll
  for (int i = 0; i < 4; ++i)
#pragma unroll
    for (int r = 0; r < 4; ++r) {
      int gm = mstart + wr * 64 + i * 16 + q * 4 + r;
      if (gm < rowend) {
#pragma unroll
        for (int j = 0; j < 2; ++j)
          out[(size_t)gm * HD + n0 + wc * 32 + j * 16 + r16] = acc[i][j][r];
      }
    }
}

extern "C" void kernel_launch(void* const* d_in, const int* in_sizes, int n_in,
                              void* d_out, int out_size, void* d_ws, size_t ws_size,
                              hipStream_t stream) {
  const float* x = (const float*)d_in[0];
  const float* w1 = (const float*)d_in[1];
  const float* w2 = (const float*)d_in[2];
  const float* w3 = (const float*)d_in[3];
  const void* bs = d_in[4];
  float* out = (float*)d_out;
  // ws: xt tiled [24*32*16KB = 12.58 MB] | up [23.07 MB]
  unsigned short* xt = (unsigned short*)d_ws;
  __hip_bfloat16* up =
      (__hip_bfloat16*)((char*)d_ws + (size_t)MAXMT * NKS1 * TILE2);

  hipMemsetAsync(d_out, 0, (size_t)out_size * sizeof(float), stream);

  cvt_xt<<<dim3(MAXMT * NKS1), dim3(256), 0, stream>>>(x, bs, xt);
  moe_gemm1<<<dim3((ID / BN1) * MAXMT), dim3(512), 0, stream>>>(xt, w1, w3, bs, up);
  moe_gemm2<<<dim3((HD / BN2) * MAXMT), dim3(512), 0, stream>>>(up, w2, bs, out);
}